// Round 13
// baseline (265.742 us; speedup 1.0000x reference)
//
#include <hip/hip_runtime.h>

typedef __attribute__((ext_vector_type(8))) short bf16x8;
typedef __attribute__((ext_vector_type(8))) unsigned short ushort8;
typedef __attribute__((ext_vector_type(4))) float f32x4;
typedef __attribute__((ext_vector_type(16))) float f32x16;
typedef unsigned short u16;
typedef unsigned int u32;

__device__ inline float bf2f(u16 u) {
    unsigned int x = ((unsigned int)u) << 16;
    float f; __builtin_memcpy(&f, &x, 4); return f;
}
__device__ inline u16 f2bf(float f) {
    unsigned int x; __builtin_memcpy(&x, &f, 4);
    unsigned int r = (x + 0x7FFFu + ((x >> 16) & 1u)) >> 16;
    return (u16)r;
}
__device__ inline u32 cvtpk(float lo, float hi) {
    u32 r;
    asm("v_cvt_pk_bf16_f32 %0, %1, %2" : "=v"(r) : "v"(lo), "v"(hi));
    return r;
}
__device__ inline void store_out(u16* p, float v) { *p = f2bf(v); }
__device__ inline void store_out(float* p, float v) { *p = v; }

// ---------------- prep: x convert + weight converts + bias concat + rope, one launch ----------------
// grid 8193: [0,3072) x f32->bf16; [3072,7680) wconv; [7680,8192) rope; 8192 bias
__global__ __launch_bounds__(256) void prep_kernel(const float* __restrict__ x,
                                                   const float* __restrict__ Wq, const float* __restrict__ Wk,
                                                   const float* __restrict__ Wv, const float* __restrict__ Wo,
                                                   const float* __restrict__ bq, const float* __restrict__ bk,
                                                   const float* __restrict__ bv, const float* __restrict__ freqs,
                                                   u16* __restrict__ xb,
                                                   u16* __restrict__ wqkv, u16* __restrict__ wob,
                                                   float* __restrict__ bqkv, float* __restrict__ rope) {
    int bid = blockIdx.x, t = threadIdx.x;
    if (bid < 7680) {
        const float* src;
        u16* dst;
        size_t j;
        if (bid < 3072) {
            src = x; dst = xb; j = (size_t)bid * 256 + t;
        } else {
            size_t i = (size_t)(bid - 3072) * 256 + t;       // 0..1179647
            int seg = (int)(i / 294912); j = i - (size_t)seg * 294912;
            src = (seg == 0) ? Wq : (seg == 1) ? Wk : (seg == 2) ? Wv : Wo;
            dst = (seg < 3) ? (wqkv + (size_t)seg * 2359296) : wob;
        }
        float4 a = *(const float4*)(src + j * 8);
        float4 b = *(const float4*)(src + j * 8 + 4);
        ushort8 o;
        o[0] = f2bf(a.x); o[1] = f2bf(a.y); o[2] = f2bf(a.z); o[3] = f2bf(a.w);
        o[4] = f2bf(b.x); o[5] = f2bf(b.y); o[6] = f2bf(b.z); o[7] = f2bf(b.w);
        *(ushort8*)(dst + j * 8) = o;
    } else if (bid < 8192) {
        int i = (bid - 7680) * 256 + t;          // 0..131071
        int s = i >> 6, j = i & 63;
        int fi = s >> 8, hi = (s >> 4) & 15, wi = s & 15;
        int pos = (j < 22) ? fi : ((j < 43) ? hi : wi);
        rope[s * 128 + j * 2]     = freqs[pos * 128 + j * 2];
        rope[s * 128 + j * 2 + 1] = freqs[pos * 128 + j * 2 + 1];
    } else {
#pragma unroll
        for (int it = 0; it < 18; ++it) {
            int j = it * 256 + t;
            bqkv[j] = (j < 1536) ? bq[j] : ((j < 3072) ? bk[j - 1536] : bv[j - 3072]);
        }
    }
}

// ---------------- 128x192 GEMM (QKV): tail-free grid 768 = one full residency wave ----------------
// 4 waves of 64x96. A: 3-buffer depth-2; B: 2-buffer depth-1. Steady vmcnt(7).
// flat grid, bijective XCD swizzle. requires (K/32) % 6 == 0, M/128 == 32.
template <typename OutT>
__global__ __launch_bounds__(256, 3) void gemm192(const u16* __restrict__ A, const u16* __restrict__ Bw,
                                                  const float* __restrict__ bias, OutT* __restrict__ C,
                                                  int M, int N, int K) {
    __shared__ __align__(16) u16 As[3][4096];    // [128][32] each
    __shared__ __align__(16) u16 Bs[2][6144];    // [192][32] each
    const int tid = threadIdx.x;
    const int w = tid >> 6, l = tid & 63;
    const int lg = l >> 4, li = l & 15;
    const int nwg = gridDim.x, cpx = nwg >> 3;
    const int swz = ((int)blockIdx.x & 7) * cpx + ((int)blockIdx.x >> 3);
    const int row0 = (swz & 31) * 128, col0 = (swz >> 5) * 192;
    const int wr = (w >> 1) * 64, wc = (w & 1) * 96;
    const int nt = K >> 5;

    f32x4 acc[4][6] = {};

    auto STAGE_A = [&](int bi, int t) {
        int k0 = t << 5;
#pragma unroll
        for (int c = 0; c < 2; ++c) {
            int idx = c * 256 + tid;
            int r = idx >> 2;
            int clog = (idx & 3) ^ ((r >> 1) & 3);
            __builtin_amdgcn_global_load_lds(
                (const __attribute__((address_space(1))) void*)(A + (size_t)(row0 + r) * K + k0 + clog * 8),
                (__attribute__((address_space(3))) void*)((char*)&As[0][0] + bi * 8192 + c * 4096 + w * 1024), 16, 0, 0);
        }
    };
    auto STAGE_B = [&](int bi, int t) {
        int k0 = t << 5;
#pragma unroll
        for (int c = 0; c < 3; ++c) {
            int idx = c * 256 + tid;
            int r = idx >> 2;                    // 0..191
            int clog = (idx & 3) ^ ((r >> 1) & 3);
            __builtin_amdgcn_global_load_lds(
                (const __attribute__((address_space(1))) void*)(Bw + (size_t)(col0 + r) * K + k0 + clog * 8),
                (__attribute__((address_space(3))) void*)((char*)&Bs[0][0] + bi * 12288 + c * 4096 + w * 1024), 16, 0, 0);
        }
    };

    const int rchunk = (lg ^ ((li >> 1) & 3)) * 8;
    STAGE_A(0, 0); STAGE_B(0, 0); STAGE_A(1, 1);

    for (int tb = 0; tb < nt; tb += 6) {
#pragma unroll
        for (int j = 0; j < 6; ++j) {
            const int t = tb + j;
            const int ai = j % 3, bi = j & 1;
            if (t + 1 < nt) STAGE_B((bi ^ 1), t + 1);
            if (t + 2 < nt) {
                STAGE_A((j + 2) % 3, t + 2);
                asm volatile("s_waitcnt vmcnt(7)" ::: "memory");
            } else if (t + 1 < nt) {
                asm volatile("s_waitcnt vmcnt(5)" ::: "memory");
            } else {
                asm volatile("s_waitcnt vmcnt(0)" ::: "memory");
            }
            __builtin_amdgcn_s_barrier();
            __builtin_amdgcn_sched_barrier(0);
            const u16* as = &As[ai][0];
            const u16* bs = &Bs[bi][0];
            bf16x8 af[4], bfr[6];
#pragma unroll
            for (int m = 0; m < 4; ++m) af[m] = *(const bf16x8*)(as + (wr + m * 16 + li) * 32 + rchunk);
#pragma unroll
            for (int n = 0; n < 6; ++n) bfr[n] = *(const bf16x8*)(bs + (wc + n * 16 + li) * 32 + rchunk);
#pragma unroll
            for (int m = 0; m < 4; ++m)
#pragma unroll
                for (int n = 0; n < 6; ++n)
                    acc[m][n] = __builtin_amdgcn_mfma_f32_16x16x32_bf16(af[m], bfr[n], acc[m][n], 0, 0, 0);
            __builtin_amdgcn_sched_barrier(0);
            __builtin_amdgcn_s_barrier();
        }
    }

#pragma unroll
    for (int m = 0; m < 4; ++m) {
#pragma unroll
        for (int n = 0; n < 6; ++n) {
#pragma unroll
            for (int j = 0; j < 4; ++j) {
                int r = row0 + wr + m * 16 + lg * 4 + j;
                int cc = col0 + wc + n * 16 + li;
                float v = acc[m][n][j] + bias[cc];
                store_out(&C[(size_t)r * N + cc], v);
            }
        }
    }
}

// ---------------- 128x128 GEMM (out-projection): triple-buffered, depth-2 counted vmcnt ----------------
// requires (K/32) % 3 == 0
template <typename OutT>
__global__ __launch_bounds__(256) void gemm_bt(const u16* __restrict__ A, const u16* __restrict__ Bw,
                                               const float* __restrict__ bias, OutT* __restrict__ C,
                                               int M, int N, int K) {
    __shared__ __align__(16) u16 As[3][4096];
    __shared__ __align__(16) u16 Bs[3][4096];
    const int tid = threadIdx.x;
    const int w = tid >> 6, l = tid & 63;
    const int lg = l >> 4, li = l & 15;
    const int row0 = blockIdx.x * 128, col0 = blockIdx.y * 128;
    const int wr = (w >> 1) * 64, wc = (w & 1) * 64;
    const int nt = K >> 5;

    f32x4 acc[4][4] = {};

    auto STAGE = [&](int bi, int t) {
        int k0 = t << 5;
#pragma unroll
        for (int c = 0; c < 2; ++c) {
            int idx = c * 256 + tid;
            int r = idx >> 2;
            int clog = (idx & 3) ^ ((r >> 1) & 3);
            __builtin_amdgcn_global_load_lds(
                (const __attribute__((address_space(1))) void*)(A + (size_t)(row0 + r) * K + k0 + clog * 8),
                (__attribute__((address_space(3))) void*)((char*)&As[0][0] + bi * 8192 + c * 4096 + w * 1024), 16, 0, 0);
            __builtin_amdgcn_global_load_lds(
                (const __attribute__((address_space(1))) void*)(Bw + (size_t)(col0 + r) * K + k0 + clog * 8),
                (__attribute__((address_space(3))) void*)((char*)&Bs[0][0] + bi * 8192 + c * 4096 + w * 1024), 16, 0, 0);
        }
    };

    const int rchunk = (lg ^ ((li >> 1) & 3)) * 8;
    STAGE(0, 0);
    STAGE(1, 1);
    for (int tb = 0; tb < nt; tb += 3) {
#pragma unroll
        for (int j = 0; j < 3; ++j) {
            const int t = tb + j;
            if (t + 2 < nt) {
                STAGE((j + 2) % 3, t + 2);
                asm volatile("s_waitcnt vmcnt(8)" ::: "memory");
            } else if (t + 1 < nt) {
                asm volatile("s_waitcnt vmcnt(4)" ::: "memory");
            } else {
                asm volatile("s_waitcnt vmcnt(0)" ::: "memory");
            }
            __builtin_amdgcn_s_barrier();
            __builtin_amdgcn_sched_barrier(0);
            const u16* as = &As[j][0];
            const u16* bs = &Bs[j][0];
            bf16x8 af[4], bfr[4];
#pragma unroll
            for (int m = 0; m < 4; ++m) af[m] = *(const bf16x8*)(as + (wr + m * 16 + li) * 32 + rchunk);
#pragma unroll
            for (int n = 0; n < 4; ++n) bfr[n] = *(const bf16x8*)(bs + (wc + n * 16 + li) * 32 + rchunk);
#pragma unroll
            for (int m = 0; m < 4; ++m)
#pragma unroll
                for (int n = 0; n < 4; ++n)
                    acc[m][n] = __builtin_amdgcn_mfma_f32_16x16x32_bf16(af[m], bfr[n], acc[m][n], 0, 0, 0);
            __builtin_amdgcn_sched_barrier(0);
            __builtin_amdgcn_s_barrier();
        }
    }

#pragma unroll
    for (int m = 0; m < 4; ++m) {
#pragma unroll
        for (int n = 0; n < 4; ++n) {
#pragma unroll
            for (int j = 0; j < 4; ++j) {
                int r = row0 + wr + m * 16 + lg * 4 + j;
                int cc = col0 + wc + n * 16 + li;
                float v = acc[m][n][j] + bias[cc];
                store_out(&C[(size_t)r * N + cc], v);
            }
        }
    }
}

// ---------------- fused rmsnorm+rope (q,k) and V transpose, one launch ----------------
// grid 5632: [0,4096) rmsrope rows; [4096,5632) vtrans tiles
__global__ __launch_bounds__(256) void rmsview_kernel(const u16* __restrict__ qkv,
                                                      const float* __restrict__ wq_n,
                                                      const float* __restrict__ wk_n,
                                                      const float* __restrict__ rope,
                                                      u16* __restrict__ qh, u16* __restrict__ kh,
                                                      u16* __restrict__ vt) {
    __shared__ __align__(16) char sm[9216];
    int t = threadIdx.x;
    if (blockIdx.x < 4096) {
        int row = blockIdx.x;              // 0..4095
        int b = row >> 11, s = row & 2047;
        const u16* pr = qkv + (size_t)row * 4608;
        int c0 = t * 6;

        float q[6], k[6];
#pragma unroll
        for (int i = 0; i < 3; ++i) {
            ushort2 uq = *(const ushort2*)(pr + c0 + 2 * i);
            ushort2 uk = *(const ushort2*)(pr + 1536 + c0 + 2 * i);
            q[2 * i] = bf2f(uq.x); q[2 * i + 1] = bf2f(uq.y);
            k[2 * i] = bf2f(uk.x); k[2 * i + 1] = bf2f(uk.y);
        }
        float sq = 0.f, sk = 0.f;
#pragma unroll
        for (int i = 0; i < 6; ++i) { sq += q[i] * q[i]; sk += k[i] * k[i]; }
#pragma unroll
        for (int off = 32; off >= 1; off >>= 1) {
            sq += __shfl_down(sq, off);
            sk += __shfl_down(sk, off);
        }
        float* red = (float*)sm;
        int w = t >> 6, l = t & 63;
        if (l == 0) { red[w] = sq; red[w + 4] = sk; }
        __syncthreads();
        float rq = rsqrtf((red[0] + red[1] + red[2] + red[3]) * (1.0f / 1536.0f) + 1e-6f);
        float rk = rsqrtf((red[4] + red[5] + red[6] + red[7]) * (1.0f / 1536.0f) + 1e-6f);

#pragma unroll
        for (int i = 0; i < 3; ++i) {
            int c = c0 + 2 * i;
            int h = c >> 7, d = c & 127;
            float cs = rope[s * 128 + d];
            float sn = rope[s * 128 + d + 1];
            float qa = q[2 * i] * rq * wq_n[c], qb = q[2 * i + 1] * rq * wq_n[c + 1];
            float ka = k[2 * i] * rk * wk_n[c], kb = k[2 * i + 1] * rk * wk_n[c + 1];
            size_t o = ((size_t)(b * 12 + h) * 2048 + s) * 128 + d;
            ushort2 qo, ko;
            qo.x = f2bf(qa * cs - qb * sn); qo.y = f2bf(qa * sn + qb * cs);
            ko.x = f2bf(ka * cs - kb * sn); ko.y = f2bf(ka * sn + kb * cs);
            *(ushort2*)(qh + o) = qo;
            *(ushort2*)(kh + o) = ko;
        }
    } else {
        // V transpose tile; kv stored PERMUTED (bits2,3 of kv%16 swapped)
        int idx = blockIdx.x - 4096;       // 0..1535
        const int s0 = (idx & 31) * 64;
        const int d0 = ((idx >> 5) & 1) * 64;
        const int bh = idx >> 6;
        const int b = bh / 12, h = bh % 12;
        u16* L = (u16*)sm;                 // [64][72]

#pragma unroll
        for (int j = 0; j < 2; ++j) {
            int p = j * 256 + t;           // 0..511
            int s = p >> 3, c8 = p & 7;
            ushort8 v8 = *(const ushort8*)(qkv + (size_t)(b * 2048 + s0 + s) * 4608 + 3072 + h * 128 + d0 + c8 * 8);
            int pb = c8 ^ ((s >> 3) & 7);
            *(ushort8*)(L + s * 72 + pb * 8) = v8;
        }
        __syncthreads();
#pragma unroll
        for (int j = 0; j < 2; ++j) {
            int p = j * 256 + t;
            int d = p >> 3, s8 = p & 7;
            ushort8 o;
#pragma unroll
            for (int i = 0; i < 8; ++i) {
                int ps = s8 * 8 + i;
                int v4 = ps & 15;
                int ls = (ps & ~15) | (v4 & 3) | ((v4 & 4) << 1) | ((v4 & 8) >> 1);  // swap bits 2,3
                o[i] = L[ls * 72 + ((((d >> 3) ^ (ls >> 3)) & 7) << 3) + (d & 7)];
            }
            *(ushort8*)(vt + (size_t)bh * 128 * 2048 + (size_t)(d0 + d) * 2048 + s0 + s8 * 8) = o;
        }
    }
}

// ---------------- flash attention (swapped-operand 32x32, 4 waves x 32 q rows, dbuf prefetch) ----------------
// flat grid 384, XCD-affinity: bh = (bid&7)*3 + (bid>>3)%3, qt = (bid>>3)/3
__global__ __launch_bounds__(256, 2) void attn_kernel(const u16* __restrict__ qh, const u16* __restrict__ kh,
                                                      const u16* __restrict__ vt, const int* __restrict__ seq_lens,
                                                      u16* __restrict__ aout) {
    const int bid = blockIdx.x;
    const int g = bid & 7, rr = bid >> 3;
    const int bh = g * 3 + rr % 3;
    const int qt = rr / 3;
    const int b = bh / 12, h = bh % 12;
    const int tid = threadIdx.x;      // 0..255
    const int w = tid >> 6, l = tid & 63;
    const int q5 = l & 31;
    const int hi = l >> 5;
    const int seqlen = seq_lens[b];

    __shared__ __align__(16) char smem[65536];  // Ks[2][64*128] | Vs[2][128*64]

    const size_t hbase = (size_t)bh * 2048 * 128;
    const u16* kb = kh + hbase;
    const u16* vtb = vt + hbase;

    const int qrow = qt * 128 + w * 32 + q5;
    bf16x8 qf[8];
    {
        const u16* qp = qh + hbase + (size_t)qrow * 128 + hi * 8;
#pragma unroll
        for (int kd = 0; kd < 8; ++kd) qf[kd] = *(const bf16x8*)(qp + kd * 16);
    }

    auto STAGE = [&](int bi, int kv0) {
#pragma unroll
        for (int i = 0; i < 4; ++i) {
            int p = i * 256 + tid;
            int kr = p >> 4, kc = p & 15;
            __builtin_amdgcn_global_load_lds(
                (const __attribute__((address_space(1))) void*)(kb + (size_t)(kv0 + kr) * 128 + ((kc ^ (kr & 15)) << 3)),
                (__attribute__((address_space(3))) void*)(smem + bi * 16384 + i * 4096 + w * 1024), 16, 0, 0);
            int vr = p >> 3, vc = p & 7;
            __builtin_amdgcn_global_load_lds(
                (const __attribute__((address_space(1))) void*)(vtb + (size_t)vr * 2048 + kv0 + ((vc ^ (vr & 7)) << 3)),
                (__attribute__((address_space(3))) void*)(smem + 32768 + bi * 16384 + i * 4096 + w * 1024), 16, 0, 0);
        }
    };

    f32x16 oacc[4] = {};
    float m_run = -3e38f, l_run = 0.f;
    const float c2 = 0.08838834764831845f * 1.44269504088896341f;

    STAGE(0, 0);
    for (int t = 0; t < 32; ++t) {
        const int cur = t & 1;
        const int kv0 = t * 64;
        if (t < 31) {
            STAGE(cur ^ 1, kv0 + 64);
            asm volatile("s_waitcnt vmcnt(8)" ::: "memory");
        } else {
            asm volatile("s_waitcnt vmcnt(0)" ::: "memory");
        }
        __builtin_amdgcn_s_barrier();
        __builtin_amdgcn_sched_barrier(0);

        const u16* Ks = (const u16*)(smem + cur * 16384);
        const u16* Vs = (const u16*)(smem + 32768 + cur * 16384);

        f32x16 sacc[2] = {};
        __builtin_amdgcn_s_setprio(1);
#pragma unroll
        for (int tt = 0; tt < 2; ++tt) {
            int row = tt * 32 + q5;
#pragma unroll
            for (int kd = 0; kd < 8; ++kd) {
                int bk = (2 * kd + hi) ^ (q5 & 15);
                bf16x8 kf = *(const bf16x8*)(Ks + row * 128 + bk * 8);
                sacc[tt] = __builtin_amdgcn_mfma_f32_32x32x16_bf16(kf, qf[kd], sacc[tt], 0, 0, 0);
            }
        }
        __builtin_amdgcn_s_setprio(0);

        if (kv0 + 64 > seqlen) {
#pragma unroll
            for (int tt = 0; tt < 2; ++tt)
#pragma unroll
                for (int m = 0; m < 4; ++m)
#pragma unroll
                    for (int r = 0; r < 4; ++r) {
                        int kv = kv0 + tt * 32 + m * 8 + hi * 4 + r;
                        if (kv >= seqlen) sacc[tt][m * 4 + r] = -1e30f;
                    }
        }

        // balanced-tree max
        float a8[8];
#pragma unroll
        for (int r = 0; r < 8; ++r)
            a8[r] = fmaxf(fmaxf(sacc[0][r], sacc[0][r + 8]), fmaxf(sacc[1][r], sacc[1][r + 8]));
        float b4_0 = fmaxf(a8[0], a8[1]), b4_1 = fmaxf(a8[2], a8[3]);
        float b4_2 = fmaxf(a8[4], a8[5]), b4_3 = fmaxf(a8[6], a8[7]);
        float pmax = fmaxf(fmaxf(b4_0, b4_1), fmaxf(b4_2, b4_3));
        pmax = fmaxf(pmax, __shfl_xor(pmax, 32));

        int defer = __all(pmax <= m_run + 62.7f);
        if (!defer) {
            float mnew = fmaxf(m_run, pmax);
            float alpha = __builtin_amdgcn_exp2f((m_run - mnew) * c2);
#pragma unroll
            for (int dt = 0; dt < 4; ++dt)
#pragma unroll
                for (int r = 0; r < 16; ++r) oacc[dt][r] *= alpha;
            l_run *= alpha;
            m_run = mnew;
        }

        float gs[8];
        u32 Wp[2][4][2];
#pragma unroll
        for (int tt = 0; tt < 2; ++tt)
#pragma unroll
            for (int m = 0; m < 4; ++m) {
                float p0 = __builtin_amdgcn_exp2f((sacc[tt][4 * m + 0] - m_run) * c2);
                float p1 = __builtin_amdgcn_exp2f((sacc[tt][4 * m + 1] - m_run) * c2);
                float p2 = __builtin_amdgcn_exp2f((sacc[tt][4 * m + 2] - m_run) * c2);
                float p3 = __builtin_amdgcn_exp2f((sacc[tt][4 * m + 3] - m_run) * c2);
                gs[tt * 4 + m] = (p0 + p1) + (p2 + p3);
                Wp[tt][m][0] = cvtpk(p0, p1);
                Wp[tt][m][1] = cvtpk(p2, p3);
            }
        float ls = ((gs[0] + gs[1]) + (gs[2] + gs[3])) + ((gs[4] + gs[5]) + (gs[6] + gs[7]));
        ls += __shfl_xor(ls, 32);
        l_run += ls;

        __builtin_amdgcn_s_setprio(1);
#pragma unroll
        for (int tt = 0; tt < 2; ++tt)
#pragma unroll
            for (int c = 0; c < 2; ++c) {
                union { u32 u[4]; bf16x8 v; } pu;
                pu.u[0] = Wp[tt][2 * c][0]; pu.u[1] = Wp[tt][2 * c][1];
                pu.u[2] = Wp[tt][2 * c + 1][0]; pu.u[3] = Wp[tt][2 * c + 1][1];
                int bk = 4 * tt + 2 * c + hi;
#pragma unroll
                for (int dt = 0; dt < 4; ++dt) {
                    int drow = dt * 32 + q5;
                    int pb = bk ^ (drow & 7);
                    bf16x8 vf = *(const bf16x8*)(Vs + drow * 64 + pb * 8);
                    oacc[dt] = __builtin_amdgcn_mfma_f32_32x32x16_bf16(vf, pu.v, oacc[dt], 0, 0, 0);
                }
            }
        __builtin_amdgcn_s_setprio(0);
        __builtin_amdgcn_sched_barrier(0);
        __builtin_amdgcn_s_barrier();
    }

    __syncthreads();
    u32* Lq = (u32*)smem + w * 2144;   // [32][67] u32 per wave
    float inv_l = 1.0f / l_run;
#pragma unroll
    for (int dt = 0; dt < 4; ++dt)
#pragma unroll
        for (int m = 0; m < 4; ++m) {
            u32 w0 = cvtpk(oacc[dt][4 * m + 0] * inv_l, oacc[dt][4 * m + 1] * inv_l);
            u32 w1 = cvtpk(oacc[dt][4 * m + 2] * inv_l, oacc[dt][4 * m + 3] * inv_l);
            int widx = dt * 16 + 4 * m + 2 * hi;
            Lq[q5 * 67 + widx] = w0;
            Lq[q5 * 67 + widx + 1] = w1;
        }
    __builtin_amdgcn_s_waitcnt(0);
#pragma unroll
    for (int pp = 0; pp < 8; ++pp) {
        int qq = pp * 4 + (l >> 4);
        int cc = l & 15;
        union { u32 u[4]; ushort8 v; } ou;
        ou.u[0] = Lq[qq * 67 + cc * 4 + 0];
        ou.u[1] = Lq[qq * 67 + cc * 4 + 1];
        ou.u[2] = Lq[qq * 67 + cc * 4 + 2];
        ou.u[3] = Lq[qq * 67 + cc * 4 + 3];
        size_t off = ((size_t)(b * 2048 + qt * 128 + w * 32 + qq)) * 1536 + h * 128 + cc * 8;
        *(ushort8*)(aout + off) = ou.v;
    }
}

// ---------------- host ----------------
extern "C" void kernel_launch(void* const* d_in, const int* in_sizes, int n_in,
                              void* d_out, int out_size, void* d_ws, size_t ws_size,
                              hipStream_t stream) {
    const float* x    = (const float*)d_in[0];
    const int* seqlen = (const int*)d_in[1];
    const float* freqs = (const float*)d_in[3];
    const float* Wq = (const float*)d_in[4];  const float* bq = (const float*)d_in[5];
    const float* Wk = (const float*)d_in[6];  const float* bk = (const float*)d_in[7];
    const float* Wv = (const float*)d_in[8];  const float* bv = (const float*)d_in[9];
    const float* Wo = (const float*)d_in[10]; const float* bo = (const float*)d_in[11];
    const float* wqn = (const float*)d_in[12];
    const float* wkn = (const float*)d_in[13];
    float* out = (float*)d_out;

    char* ws = (char*)d_ws;
    u16*   xb   = (u16*)(ws);                    // 12,582,912
    u16*   wqkv = (u16*)(ws + 12582912);         // 14,155,776
    u16*   wob  = (u16*)(ws + 26738688);         //  4,718,592
    float* bqkv = (float*)(ws + 31457280);       //     18,432
    float* rope = (float*)(ws + 31475712);       //  1,048,576
    u16*   qkv  = (u16*)(ws + 32524288);         // 37,748,736
    u16*   qhb  = (u16*)(ws + 70273024);         // 12,582,912
    u16*   khb  = (u16*)(ws + 82855936);         // 12,582,912
    u16*   vtb  = (u16*)(ws + 95438848);         // 12,582,912 (V^T [24][128][2048], kv-permuted)
    u16*   aob  = (u16*)(ws + 108021760);        // 12,582,912  (end 120,604,672)

    prep_kernel<<<8193, 256, 0, stream>>>(x, Wq, Wk, Wv, Wo, bq, bk, bv, freqs, xb, wqkv, wob, bqkv, rope);

    // QKV projection: 128x192 tail-free GEMM (flat grid 768 = 3 blocks/CU x 256 CU, one round)
    gemm192<u16><<<768, 256, 0, stream>>>(xb, wqkv, bqkv, qkv, 4096, 4608, 1536);
    rmsview_kernel<<<5632, 256, 0, stream>>>(qkv, wqn, wkn, rope, qhb, khb, vtb);
    attn_kernel<<<384, 256, 0, stream>>>(qhb, khb, vtb, seqlen, aob);
    gemm_bt<float><<<dim3(32, 12), 256, 0, stream>>>(aob, wob, bo, out, 4096, 1536, 1536);
}

// Round 14
// 215.523 us; speedup vs baseline: 1.2330x; 1.2330x over previous
//
#include <hip/hip_runtime.h>

typedef __attribute__((ext_vector_type(8))) short bf16x8;
typedef __attribute__((ext_vector_type(8))) unsigned short ushort8;
typedef __attribute__((ext_vector_type(4))) float f32x4;
typedef __attribute__((ext_vector_type(16))) float f32x16;
typedef unsigned short u16;
typedef unsigned int u32;

__device__ inline float bf2f(u16 u) {
    unsigned int x = ((unsigned int)u) << 16;
    float f; __builtin_memcpy(&f, &x, 4); return f;
}
__device__ inline u16 f2bf(float f) {
    unsigned int x; __builtin_memcpy(&x, &f, 4);
    unsigned int r = (x + 0x7FFFu + ((x >> 16) & 1u)) >> 16;
    return (u16)r;
}
__device__ inline u32 cvtpk(float lo, float hi) {
    u32 r;
    asm("v_cvt_pk_bf16_f32 %0, %1, %2" : "=v"(r) : "v"(lo), "v"(hi));
    return r;
}
__device__ inline void store_out(u16* p, float v) { *p = f2bf(v); }
__device__ inline void store_out(float* p, float v) { *p = v; }

// ---------------- prep: x convert + weight converts + bias concat + rope, one launch ----------------
// grid 8193: [0,3072) x f32->bf16; [3072,7680) wconv; [7680,8192) rope; 8192 bias
__global__ __launch_bounds__(256) void prep_kernel(const float* __restrict__ x,
                                                   const float* __restrict__ Wq, const float* __restrict__ Wk,
                                                   const float* __restrict__ Wv, const float* __restrict__ Wo,
                                                   const float* __restrict__ bq, const float* __restrict__ bk,
                                                   const float* __restrict__ bv, const float* __restrict__ freqs,
                                                   u16* __restrict__ xb,
                                                   u16* __restrict__ wqkv, u16* __restrict__ wob,
                                                   float* __restrict__ bqkv, float* __restrict__ rope) {
    int bid = blockIdx.x, t = threadIdx.x;
    if (bid < 7680) {
        const float* src;
        u16* dst;
        size_t j;
        if (bid < 3072) {
            src = x; dst = xb; j = (size_t)bid * 256 + t;
        } else {
            size_t i = (size_t)(bid - 3072) * 256 + t;       // 0..1179647
            int seg = (int)(i / 294912); j = i - (size_t)seg * 294912;
            src = (seg == 0) ? Wq : (seg == 1) ? Wk : (seg == 2) ? Wv : Wo;
            dst = (seg < 3) ? (wqkv + (size_t)seg * 2359296) : wob;
        }
        float4 a = *(const float4*)(src + j * 8);
        float4 b = *(const float4*)(src + j * 8 + 4);
        ushort8 o;
        o[0] = f2bf(a.x); o[1] = f2bf(a.y); o[2] = f2bf(a.z); o[3] = f2bf(a.w);
        o[4] = f2bf(b.x); o[5] = f2bf(b.y); o[6] = f2bf(b.z); o[7] = f2bf(b.w);
        *(ushort8*)(dst + j * 8) = o;
    } else if (bid < 8192) {
        int i = (bid - 7680) * 256 + t;          // 0..131071
        int s = i >> 6, j = i & 63;
        int fi = s >> 8, hi = (s >> 4) & 15, wi = s & 15;
        int pos = (j < 22) ? fi : ((j < 43) ? hi : wi);
        rope[s * 128 + j * 2]     = freqs[pos * 128 + j * 2];
        rope[s * 128 + j * 2 + 1] = freqs[pos * 128 + j * 2 + 1];
    } else {
#pragma unroll
        for (int it = 0; it < 18; ++it) {
            int j = it * 256 + t;
            bqkv[j] = (j < 1536) ? bq[j] : ((j < 3072) ? bk[j - 1536] : bv[j - 3072]);
        }
    }
}

// ---------------- 128x128 GEMM (QKV): double-buffered, depth-1, 5 blocks/CU => tail-free single round ----------------
// requires (K/32) even
template <typename OutT>
__global__ __launch_bounds__(256) void gemm_db(const u16* __restrict__ A, const u16* __restrict__ Bw,
                                               const float* __restrict__ bias, OutT* __restrict__ C,
                                               int M, int N, int K) {
    __shared__ __align__(16) u16 As[2][4096];
    __shared__ __align__(16) u16 Bs[2][4096];
    const int tid = threadIdx.x;
    const int w = tid >> 6, l = tid & 63;
    const int lg = l >> 4, li = l & 15;
    const int row0 = blockIdx.x * 128, col0 = blockIdx.y * 128;
    const int wr = (w >> 1) * 64, wc = (w & 1) * 64;
    const int nt = K >> 5;

    f32x4 acc[4][4] = {};

    auto STAGE = [&](int bi, int t) {
        int k0 = t << 5;
#pragma unroll
        for (int c = 0; c < 2; ++c) {
            int idx = c * 256 + tid;
            int r = idx >> 2;
            int clog = (idx & 3) ^ ((r >> 1) & 3);
            __builtin_amdgcn_global_load_lds(
                (const __attribute__((address_space(1))) void*)(A + (size_t)(row0 + r) * K + k0 + clog * 8),
                (__attribute__((address_space(3))) void*)((char*)&As[0][0] + bi * 8192 + c * 4096 + w * 1024), 16, 0, 0);
            __builtin_amdgcn_global_load_lds(
                (const __attribute__((address_space(1))) void*)(Bw + (size_t)(col0 + r) * K + k0 + clog * 8),
                (__attribute__((address_space(3))) void*)((char*)&Bs[0][0] + bi * 8192 + c * 4096 + w * 1024), 16, 0, 0);
        }
    };

    const int rchunk = (lg ^ ((li >> 1) & 3)) * 8;
    STAGE(0, 0);
    for (int tb = 0; tb < nt; tb += 2) {
#pragma unroll
        for (int j = 0; j < 2; ++j) {
            const int t = tb + j;
            if (t + 1 < nt) {
                STAGE((j + 1) & 1, t + 1);
                asm volatile("s_waitcnt vmcnt(4)" ::: "memory");
            } else {
                asm volatile("s_waitcnt vmcnt(0)" ::: "memory");
            }
            __builtin_amdgcn_s_barrier();
            __builtin_amdgcn_sched_barrier(0);
            const u16* as = &As[j][0];
            const u16* bs = &Bs[j][0];
            bf16x8 af[4], bfr[4];
#pragma unroll
            for (int m = 0; m < 4; ++m) af[m] = *(const bf16x8*)(as + (wr + m * 16 + li) * 32 + rchunk);
#pragma unroll
            for (int n = 0; n < 4; ++n) bfr[n] = *(const bf16x8*)(bs + (wc + n * 16 + li) * 32 + rchunk);
#pragma unroll
            for (int m = 0; m < 4; ++m)
#pragma unroll
                for (int n = 0; n < 4; ++n)
                    acc[m][n] = __builtin_amdgcn_mfma_f32_16x16x32_bf16(af[m], bfr[n], acc[m][n], 0, 0, 0);
            __builtin_amdgcn_sched_barrier(0);
            __builtin_amdgcn_s_barrier();
        }
    }

#pragma unroll
    for (int m = 0; m < 4; ++m) {
#pragma unroll
        for (int n = 0; n < 4; ++n) {
#pragma unroll
            for (int j = 0; j < 4; ++j) {
                int r = row0 + wr + m * 16 + lg * 4 + j;
                int cc = col0 + wc + n * 16 + li;
                float v = acc[m][n][j] + bias[cc];
                store_out(&C[(size_t)r * N + cc], v);
            }
        }
    }
}

// ---------------- 128x128 GEMM (out-projection): triple-buffered, depth-2 counted vmcnt ----------------
// requires (K/32) % 3 == 0
template <typename OutT>
__global__ __launch_bounds__(256) void gemm_bt(const u16* __restrict__ A, const u16* __restrict__ Bw,
                                               const float* __restrict__ bias, OutT* __restrict__ C,
                                               int M, int N, int K) {
    __shared__ __align__(16) u16 As[3][4096];
    __shared__ __align__(16) u16 Bs[3][4096];
    const int tid = threadIdx.x;
    const int w = tid >> 6, l = tid & 63;
    const int lg = l >> 4, li = l & 15;
    const int row0 = blockIdx.x * 128, col0 = blockIdx.y * 128;
    const int wr = (w >> 1) * 64, wc = (w & 1) * 64;
    const int nt = K >> 5;

    f32x4 acc[4][4] = {};

    auto STAGE = [&](int bi, int t) {
        int k0 = t << 5;
#pragma unroll
        for (int c = 0; c < 2; ++c) {
            int idx = c * 256 + tid;
            int r = idx >> 2;
            int clog = (idx & 3) ^ ((r >> 1) & 3);
            __builtin_amdgcn_global_load_lds(
                (const __attribute__((address_space(1))) void*)(A + (size_t)(row0 + r) * K + k0 + clog * 8),
                (__attribute__((address_space(3))) void*)((char*)&As[0][0] + bi * 8192 + c * 4096 + w * 1024), 16, 0, 0);
            __builtin_amdgcn_global_load_lds(
                (const __attribute__((address_space(1))) void*)(Bw + (size_t)(col0 + r) * K + k0 + clog * 8),
                (__attribute__((address_space(3))) void*)((char*)&Bs[0][0] + bi * 8192 + c * 4096 + w * 1024), 16, 0, 0);
        }
    };

    const int rchunk = (lg ^ ((li >> 1) & 3)) * 8;
    STAGE(0, 0);
    STAGE(1, 1);
    for (int tb = 0; tb < nt; tb += 3) {
#pragma unroll
        for (int j = 0; j < 3; ++j) {
            const int t = tb + j;
            if (t + 2 < nt) {
                STAGE((j + 2) % 3, t + 2);
                asm volatile("s_waitcnt vmcnt(8)" ::: "memory");
            } else if (t + 1 < nt) {
                asm volatile("s_waitcnt vmcnt(4)" ::: "memory");
            } else {
                asm volatile("s_waitcnt vmcnt(0)" ::: "memory");
            }
            __builtin_amdgcn_s_barrier();
            __builtin_amdgcn_sched_barrier(0);
            const u16* as = &As[j][0];
            const u16* bs = &Bs[j][0];
            bf16x8 af[4], bfr[4];
#pragma unroll
            for (int m = 0; m < 4; ++m) af[m] = *(const bf16x8*)(as + (wr + m * 16 + li) * 32 + rchunk);
#pragma unroll
            for (int n = 0; n < 4; ++n) bfr[n] = *(const bf16x8*)(bs + (wc + n * 16 + li) * 32 + rchunk);
#pragma unroll
            for (int m = 0; m < 4; ++m)
#pragma unroll
                for (int n = 0; n < 4; ++n)
                    acc[m][n] = __builtin_amdgcn_mfma_f32_16x16x32_bf16(af[m], bfr[n], acc[m][n], 0, 0, 0);
            __builtin_amdgcn_sched_barrier(0);
            __builtin_amdgcn_s_barrier();
        }
    }

#pragma unroll
    for (int m = 0; m < 4; ++m) {
#pragma unroll
        for (int n = 0; n < 4; ++n) {
#pragma unroll
            for (int j = 0; j < 4; ++j) {
                int r = row0 + wr + m * 16 + lg * 4 + j;
                int cc = col0 + wc + n * 16 + li;
                float v = acc[m][n][j] + bias[cc];
                store_out(&C[(size_t)r * N + cc], v);
            }
        }
    }
}

// ---------------- fused rmsnorm+rope (q,k) and V transpose, one launch ----------------
// grid 5632: [0,4096) rmsrope rows; [4096,5632) vtrans tiles
__global__ __launch_bounds__(256) void rmsview_kernel(const u16* __restrict__ qkv,
                                                      const float* __restrict__ wq_n,
                                                      const float* __restrict__ wk_n,
                                                      const float* __restrict__ rope,
                                                      u16* __restrict__ qh, u16* __restrict__ kh,
                                                      u16* __restrict__ vt) {
    __shared__ __align__(16) char sm[9216];
    int t = threadIdx.x;
    if (blockIdx.x < 4096) {
        int row = blockIdx.x;              // 0..4095
        int b = row >> 11, s = row & 2047;
        const u16* pr = qkv + (size_t)row * 4608;
        int c0 = t * 6;

        float q[6], k[6];
#pragma unroll
        for (int i = 0; i < 3; ++i) {
            ushort2 uq = *(const ushort2*)(pr + c0 + 2 * i);
            ushort2 uk = *(const ushort2*)(pr + 1536 + c0 + 2 * i);
            q[2 * i] = bf2f(uq.x); q[2 * i + 1] = bf2f(uq.y);
            k[2 * i] = bf2f(uk.x); k[2 * i + 1] = bf2f(uk.y);
        }
        float sq = 0.f, sk = 0.f;
#pragma unroll
        for (int i = 0; i < 6; ++i) { sq += q[i] * q[i]; sk += k[i] * k[i]; }
#pragma unroll
        for (int off = 32; off >= 1; off >>= 1) {
            sq += __shfl_down(sq, off);
            sk += __shfl_down(sk, off);
        }
        float* red = (float*)sm;
        int w = t >> 6, l = t & 63;
        if (l == 0) { red[w] = sq; red[w + 4] = sk; }
        __syncthreads();
        float rq = rsqrtf((red[0] + red[1] + red[2] + red[3]) * (1.0f / 1536.0f) + 1e-6f);
        float rk = rsqrtf((red[4] + red[5] + red[6] + red[7]) * (1.0f / 1536.0f) + 1e-6f);

#pragma unroll
        for (int i = 0; i < 3; ++i) {
            int c = c0 + 2 * i;
            int h = c >> 7, d = c & 127;
            float cs = rope[s * 128 + d];
            float sn = rope[s * 128 + d + 1];
            float qa = q[2 * i] * rq * wq_n[c], qb = q[2 * i + 1] * rq * wq_n[c + 1];
            float ka = k[2 * i] * rk * wk_n[c], kb = k[2 * i + 1] * rk * wk_n[c + 1];
            size_t o = ((size_t)(b * 12 + h) * 2048 + s) * 128 + d;
            ushort2 qo, ko;
            qo.x = f2bf(qa * cs - qb * sn); qo.y = f2bf(qa * sn + qb * cs);
            ko.x = f2bf(ka * cs - kb * sn); ko.y = f2bf(ka * sn + kb * cs);
            *(ushort2*)(qh + o) = qo;
            *(ushort2*)(kh + o) = ko;
        }
    } else {
        // V transpose tile; kv stored PERMUTED (bits2,3 of kv%16 swapped)
        int idx = blockIdx.x - 4096;       // 0..1535
        const int s0 = (idx & 31) * 64;
        const int d0 = ((idx >> 5) & 1) * 64;
        const int bh = idx >> 6;
        const int b = bh / 12, h = bh % 12;
        u16* L = (u16*)sm;                 // [64][72]

#pragma unroll
        for (int j = 0; j < 2; ++j) {
            int p = j * 256 + t;           // 0..511
            int s = p >> 3, c8 = p & 7;
            ushort8 v8 = *(const ushort8*)(qkv + (size_t)(b * 2048 + s0 + s) * 4608 + 3072 + h * 128 + d0 + c8 * 8);
            int pb = c8 ^ ((s >> 3) & 7);
            *(ushort8*)(L + s * 72 + pb * 8) = v8;
        }
        __syncthreads();
#pragma unroll
        for (int j = 0; j < 2; ++j) {
            int p = j * 256 + t;
            int d = p >> 3, s8 = p & 7;
            ushort8 o;
#pragma unroll
            for (int i = 0; i < 8; ++i) {
                int ps = s8 * 8 + i;
                int v4 = ps & 15;
                int ls = (ps & ~15) | (v4 & 3) | ((v4 & 4) << 1) | ((v4 & 8) >> 1);  // swap bits 2,3
                o[i] = L[ls * 72 + ((((d >> 3) ^ (ls >> 3)) & 7) << 3) + (d & 7)];
            }
            *(ushort8*)(vt + (size_t)bh * 128 * 2048 + (size_t)(d0 + d) * 2048 + s0 + s8 * 8) = o;
        }
    }
}

// ---------------- flash attention (swapped-operand 32x32, 4 waves x 32 q rows, dbuf prefetch) ----------------
// flat grid 384, XCD-affinity: bh = (bid&7)*3 + (bid>>3)%3, qt = (bid>>3)/3
__global__ __launch_bounds__(256, 2) void attn_kernel(const u16* __restrict__ qh, const u16* __restrict__ kh,
                                                      const u16* __restrict__ vt, const int* __restrict__ seq_lens,
                                                      u16* __restrict__ aout) {
    const int bid = blockIdx.x;
    const int g = bid & 7, rr = bid >> 3;
    const int bh = g * 3 + rr % 3;
    const int qt = rr / 3;
    const int b = bh / 12, h = bh % 12;
    const int tid = threadIdx.x;      // 0..255
    const int w = tid >> 6, l = tid & 63;
    const int q5 = l & 31;
    const int hi = l >> 5;
    const int seqlen = seq_lens[b];

    __shared__ __align__(16) char smem[65536];  // Ks[2][64*128] | Vs[2][128*64]

    const size_t hbase = (size_t)bh * 2048 * 128;
    const u16* kb = kh + hbase;
    const u16* vtb = vt + hbase;

    const int qrow = qt * 128 + w * 32 + q5;
    bf16x8 qf[8];
    {
        const u16* qp = qh + hbase + (size_t)qrow * 128 + hi * 8;
#pragma unroll
        for (int kd = 0; kd < 8; ++kd) qf[kd] = *(const bf16x8*)(qp + kd * 16);
    }

    auto STAGE = [&](int bi, int kv0) {
#pragma unroll
        for (int i = 0; i < 4; ++i) {
            int p = i * 256 + tid;
            int kr = p >> 4, kc = p & 15;
            __builtin_amdgcn_global_load_lds(
                (const __attribute__((address_space(1))) void*)(kb + (size_t)(kv0 + kr) * 128 + ((kc ^ (kr & 15)) << 3)),
                (__attribute__((address_space(3))) void*)(smem + bi * 16384 + i * 4096 + w * 1024), 16, 0, 0);
            int vr = p >> 3, vc = p & 7;
            __builtin_amdgcn_global_load_lds(
                (const __attribute__((address_space(1))) void*)(vtb + (size_t)vr * 2048 + kv0 + ((vc ^ (vr & 7)) << 3)),
                (__attribute__((address_space(3))) void*)(smem + 32768 + bi * 16384 + i * 4096 + w * 1024), 16, 0, 0);
        }
    };

    f32x16 oacc[4] = {};
    float m_run = -3e38f, l_run = 0.f;
    const float c2 = 0.08838834764831845f * 1.44269504088896341f;

    STAGE(0, 0);
    for (int t = 0; t < 32; ++t) {
        const int cur = t & 1;
        const int kv0 = t * 64;
        if (t < 31) {
            STAGE(cur ^ 1, kv0 + 64);
            asm volatile("s_waitcnt vmcnt(8)" ::: "memory");
        } else {
            asm volatile("s_waitcnt vmcnt(0)" ::: "memory");
        }
        __builtin_amdgcn_s_barrier();
        __builtin_amdgcn_sched_barrier(0);

        const u16* Ks = (const u16*)(smem + cur * 16384);
        const u16* Vs = (const u16*)(smem + 32768 + cur * 16384);

        f32x16 sacc[2] = {};
        __builtin_amdgcn_s_setprio(1);
#pragma unroll
        for (int tt = 0; tt < 2; ++tt) {
            int row = tt * 32 + q5;
#pragma unroll
            for (int kd = 0; kd < 8; ++kd) {
                int bk = (2 * kd + hi) ^ (q5 & 15);
                bf16x8 kf = *(const bf16x8*)(Ks + row * 128 + bk * 8);
                sacc[tt] = __builtin_amdgcn_mfma_f32_32x32x16_bf16(kf, qf[kd], sacc[tt], 0, 0, 0);
            }
        }
        __builtin_amdgcn_s_setprio(0);

        if (kv0 + 64 > seqlen) {
#pragma unroll
            for (int tt = 0; tt < 2; ++tt)
#pragma unroll
                for (int m = 0; m < 4; ++m)
#pragma unroll
                    for (int r = 0; r < 4; ++r) {
                        int kv = kv0 + tt * 32 + m * 8 + hi * 4 + r;
                        if (kv >= seqlen) sacc[tt][m * 4 + r] = -1e30f;
                    }
        }

        // balanced-tree max
        float a8[8];
#pragma unroll
        for (int r = 0; r < 8; ++r)
            a8[r] = fmaxf(fmaxf(sacc[0][r], sacc[0][r + 8]), fmaxf(sacc[1][r], sacc[1][r + 8]));
        float b4_0 = fmaxf(a8[0], a8[1]), b4_1 = fmaxf(a8[2], a8[3]);
        float b4_2 = fmaxf(a8[4], a8[5]), b4_3 = fmaxf(a8[6], a8[7]);
        float pmax = fmaxf(fmaxf(b4_0, b4_1), fmaxf(b4_2, b4_3));
        pmax = fmaxf(pmax, __shfl_xor(pmax, 32));

        int defer = __all(pmax <= m_run + 62.7f);
        if (!defer) {
            float mnew = fmaxf(m_run, pmax);
            float alpha = __builtin_amdgcn_exp2f((m_run - mnew) * c2);
#pragma unroll
            for (int dt = 0; dt < 4; ++dt)
#pragma unroll
                for (int r = 0; r < 16; ++r) oacc[dt][r] *= alpha;
            l_run *= alpha;
            m_run = mnew;
        }

        float gs[8];
        u32 Wp[2][4][2];
#pragma unroll
        for (int tt = 0; tt < 2; ++tt)
#pragma unroll
            for (int m = 0; m < 4; ++m) {
                float p0 = __builtin_amdgcn_exp2f((sacc[tt][4 * m + 0] - m_run) * c2);
                float p1 = __builtin_amdgcn_exp2f((sacc[tt][4 * m + 1] - m_run) * c2);
                float p2 = __builtin_amdgcn_exp2f((sacc[tt][4 * m + 2] - m_run) * c2);
                float p3 = __builtin_amdgcn_exp2f((sacc[tt][4 * m + 3] - m_run) * c2);
                gs[tt * 4 + m] = (p0 + p1) + (p2 + p3);
                Wp[tt][m][0] = cvtpk(p0, p1);
                Wp[tt][m][1] = cvtpk(p2, p3);
            }
        float ls = ((gs[0] + gs[1]) + (gs[2] + gs[3])) + ((gs[4] + gs[5]) + (gs[6] + gs[7]));
        ls += __shfl_xor(ls, 32);
        l_run += ls;

        __builtin_amdgcn_s_setprio(1);
#pragma unroll
        for (int tt = 0; tt < 2; ++tt)
#pragma unroll
            for (int c = 0; c < 2; ++c) {
                union { u32 u[4]; bf16x8 v; } pu;
                pu.u[0] = Wp[tt][2 * c][0]; pu.u[1] = Wp[tt][2 * c][1];
                pu.u[2] = Wp[tt][2 * c + 1][0]; pu.u[3] = Wp[tt][2 * c + 1][1];
                int bk = 4 * tt + 2 * c + hi;
#pragma unroll
                for (int dt = 0; dt < 4; ++dt) {
                    int drow = dt * 32 + q5;
                    int pb = bk ^ (drow & 7);
                    bf16x8 vf = *(const bf16x8*)(Vs + drow * 64 + pb * 8);
                    oacc[dt] = __builtin_amdgcn_mfma_f32_32x32x16_bf16(vf, pu.v, oacc[dt], 0, 0, 0);
                }
            }
        __builtin_amdgcn_s_setprio(0);
        __builtin_amdgcn_sched_barrier(0);
        __builtin_amdgcn_s_barrier();
    }

    __syncthreads();
    u32* Lq = (u32*)smem + w * 2144;   // [32][67] u32 per wave
    float inv_l = 1.0f / l_run;
#pragma unroll
    for (int dt = 0; dt < 4; ++dt)
#pragma unroll
        for (int m = 0; m < 4; ++m) {
            u32 w0 = cvtpk(oacc[dt][4 * m + 0] * inv_l, oacc[dt][4 * m + 1] * inv_l);
            u32 w1 = cvtpk(oacc[dt][4 * m + 2] * inv_l, oacc[dt][4 * m + 3] * inv_l);
            int widx = dt * 16 + 4 * m + 2 * hi;
            Lq[q5 * 67 + widx] = w0;
            Lq[q5 * 67 + widx + 1] = w1;
        }
    __builtin_amdgcn_s_waitcnt(0);
#pragma unroll
    for (int pp = 0; pp < 8; ++pp) {
        int qq = pp * 4 + (l >> 4);
        int cc = l & 15;
        union { u32 u[4]; ushort8 v; } ou;
        ou.u[0] = Lq[qq * 67 + cc * 4 + 0];
        ou.u[1] = Lq[qq * 67 + cc * 4 + 1];
        ou.u[2] = Lq[qq * 67 + cc * 4 + 2];
        ou.u[3] = Lq[qq * 67 + cc * 4 + 3];
        size_t off = ((size_t)(b * 2048 + qt * 128 + w * 32 + qq)) * 1536 + h * 128 + cc * 8;
        *(ushort8*)(aout + off) = ou.v;
    }
}

// ---------------- host ----------------
extern "C" void kernel_launch(void* const* d_in, const int* in_sizes, int n_in,
                              void* d_out, int out_size, void* d_ws, size_t ws_size,
                              hipStream_t stream) {
    const float* x    = (const float*)d_in[0];
    const int* seqlen = (const int*)d_in[1];
    const float* freqs = (const float*)d_in[3];
    const float* Wq = (const float*)d_in[4];  const float* bq = (const float*)d_in[5];
    const float* Wk = (const float*)d_in[6];  const float* bk = (const float*)d_in[7];
    const float* Wv = (const float*)d_in[8];  const float* bv = (const float*)d_in[9];
    const float* Wo = (const float*)d_in[10]; const float* bo = (const float*)d_in[11];
    const float* wqn = (const float*)d_in[12];
    const float* wkn = (const float*)d_in[13];
    float* out = (float*)d_out;

    char* ws = (char*)d_ws;
    u16*   xb   = (u16*)(ws);                    // 12,582,912
    u16*   wqkv = (u16*)(ws + 12582912);         // 14,155,776
    u16*   wob  = (u16*)(ws + 26738688);         //  4,718,592
    float* bqkv = (float*)(ws + 31457280);       //     18,432
    float* rope = (float*)(ws + 31475712);       //  1,048,576
    u16*   qkv  = (u16*)(ws + 32524288);         // 37,748,736
    u16*   qhb  = (u16*)(ws + 70273024);         // 12,582,912
    u16*   khb  = (u16*)(ws + 82855936);         // 12,582,912
    u16*   vtb  = (u16*)(ws + 95438848);         // 12,582,912 (V^T [24][128][2048], kv-permuted)
    u16*   aob  = (u16*)(ws + 108021760);        // 12,582,912  (end 120,604,672)

    prep_kernel<<<8193, 256, 0, stream>>>(x, Wq, Wk, Wv, Wo, bq, bk, bv, freqs, xb, wqkv, wob, bqkv, rope);

    // QKV projection: 128x128 double-buffered, 5 blocks/CU => all 1152 blocks co-resident
    gemm_db<u16><<<dim3(32, 36), 256, 0, stream>>>(xb, wqkv, bqkv, qkv, 4096, 4608, 1536);
    rmsview_kernel<<<5632, 256, 0, stream>>>(qkv, wqn, wkn, rope, qhb, khb, vtb);
    attn_kernel<<<384, 256, 0, stream>>>(qhb, khb, vtb, seqlen, aob);
    gemm_bt<float><<<dim3(32, 12), 256, 0, stream>>>(aob, wob, bo, out, 4096, 1536, 1536);
}